// Round 10
// baseline (1599.546 us; speedup 1.0000x reference)
//
#include <hip/hip_runtime.h>
#include <math.h>

#define T_DIM 2048
#define B_DIM 8
#define D_DIM 1024
#define N_DIM 64
#define NCHUNK 16
#define CHUNK_LEN 128              // T_DIM / NCHUNK
#define DECAY 0.9f
#define EPS 1e-8f
#define RADIUS 0.5f

// ---- diagnostic in-kernel repeat counts (idempotent; revert next round) ----
#define SPEC_REP 24
#define BUILD_REP 8
#define PROJ_REP 4
#define CARRY_REP 24
#define SCAN_REP 4

typedef __attribute__((ext_vector_type(8))) short short8;   // bf16x8 MFMA frag
typedef __attribute__((ext_vector_type(4))) float f32x4;

static __device__ __forceinline__ unsigned short f2bf(float f) {
    unsigned u = __float_as_uint(f);
    u += 0x7FFFu + ((u >> 16) & 1u);          // RNE
    return (unsigned short)(u >> 16);
}
static __device__ __forceinline__ float bf2f(unsigned short h) {
    return __uint_as_float(((unsigned)h) << 16);
}

// counted barrier: flush LDS writes, sync waves, do NOT drain vmcnt (T4)
static __device__ __forceinline__ void bar_lgkm() {
    asm volatile("s_waitcnt lgkmcnt(0)" ::: "memory");
    __builtin_amdgcn_s_barrier();
    asm volatile("" ::: "memory");
}

// ---------------- spectral norm scale (2 blocks: k and v) ----------------
__global__ __launch_bounds__(1024)
void spectral_kernel(const float* __restrict__ Wk,
                     const float* __restrict__ Wv,
                     const float* __restrict__ uk,
                     const float* __restrict__ uv,
                     float* __restrict__ scale_out) {
    const float* W  = (blockIdx.x == 0) ? Wk : Wv;
    const float* u0 = (blockIdx.x == 0) ? uk : uv;
    int tid = threadIdx.x;       // 0..1023 = d
    int lane = tid & 63;
    int wid = tid >> 6;          // 0..15
    __shared__ float u_s[N_DIM];
    __shared__ float v_s[D_DIM];
    __shared__ float t_s[N_DIM];
    __shared__ float red[16];
    __shared__ float bcs;
    for (int rep = 0; rep < SPEC_REP; ++rep) {
        if (tid < N_DIM) {
            float uu0 = u0[tid];
            asm volatile("" : "+v"(uu0));
            u_s[tid] = uu0;
        }
        __syncthreads();
        for (int iter = 0; iter < 3; ++iter) {
            float acc = 0.f;
            #pragma unroll
            for (int nn = 0; nn < N_DIM; ++nn)
                acc += W[nn * D_DIM + tid] * u_s[nn];
            float ss = acc * acc;
            #pragma unroll
            for (int o = 32; o > 0; o >>= 1) ss += __shfl_xor(ss, o, 64);
            if (lane == 0) red[wid] = ss;
            __syncthreads();
            if (tid == 0) {
                float tot = 0.f;
                #pragma unroll
                for (int w2 = 0; w2 < 16; ++w2) tot += red[w2];
                bcs = 1.0f / (sqrtf(tot) + EPS);
            }
            __syncthreads();
            v_s[tid] = acc * bcs;
            __syncthreads();
            #pragma unroll
            for (int rr = 0; rr < 4; ++rr) {
                int r = wid * 4 + rr;
                float a = 0.f;
                #pragma unroll
                for (int e = 0; e < 16; ++e)
                    a += W[r * D_DIM + lane + 64 * e] * v_s[lane + 64 * e];
                #pragma unroll
                for (int o = 32; o > 0; o >>= 1) a += __shfl_xor(a, o, 64);
                if (lane == 0) t_s[r] = a;
            }
            __syncthreads();
            if (wid == 0) {
                float uu = t_s[lane];
                float s2 = uu * uu;
                #pragma unroll
                for (int o = 32; o > 0; o >>= 1) s2 += __shfl_xor(s2, o, 64);
                float inv = 1.0f / (sqrtf(__shfl(s2, 0, 64)) + EPS);
                u_s[lane] = uu * inv;
            }
            __syncthreads();
        }
        if (wid == 0) {
            float val = t_s[lane] * u_s[lane];
            #pragma unroll
            for (int o = 32; o > 0; o >>= 1) val += __shfl_xor(val, o, 64);
            if (lane == 0) scale_out[blockIdx.x] = RADIUS / (fabsf(val) + EPS);
        }
        __syncthreads();
    }
}

// ------- build bf16 hi/lo of fused scaled W in MFMA-FRAGMENT-MAJOR order -------
__global__ __launch_bounds__(256)
void build_wt_kernel(const float* __restrict__ Wk,
                     const float* __restrict__ Wv,
                     const float* __restrict__ Wq,
                     const float* __restrict__ scale,
                     unsigned short* __restrict__ BPh,
                     unsigned short* __restrict__ BPl) {
    int c = blockIdx.x;           // 0..191 (output col)
    int tid = threadIdx.x;        // 0..255, 4 k-values each
    for (int rep = 0; rep < BUILD_REP; ++rep) {
        const float* src;
        float sc;
        if (c < 64)       { src = Wk + (size_t)c * D_DIM;         sc = scale[0]; }
        else if (c < 128) { src = Wv + (size_t)(c - 64) * D_DIM;  sc = scale[1]; }
        else              { src = Wq + (size_t)(c - 128) * D_DIM; sc = 1.0f; }
        asm volatile("" : "+v"(sc));
        int g = c >> 4;
        int fl = c & 15;
        float4 w = *(const float4*)(src + tid * 4);
        float vals[4] = {w.x * sc, w.y * sc, w.z * sc, w.w * sc};
        #pragma unroll
        for (int e4 = 0; e4 < 4; ++e4) {
            int k = tid * 4 + e4;
            unsigned short h = f2bf(vals[e4]);
            unsigned short l = f2bf(vals[e4] - bf2f(h));
            int s  = k >> 6;
            int kk = (k >> 5) & 1;
            int flh = (k >> 3) & 3;
            int e  = k & 7;
            size_t idx = (size_t)g * 16384 + s * 1024 + kk * 512 + (flh * 16 + fl) * 8 + e;
            BPh[idx] = h;
            BPl[idx] = l;
        }
    }
}

// ------------- projections via split-bf16 MFMA (R9 structure + repeat) -------------
#define PBM 32
#define KSTAGE 128
__global__ __launch_bounds__(256)
void proj_mfma_kernel(const float* __restrict__ x,
                      const unsigned short* __restrict__ BPh,
                      const unsigned short* __restrict__ BPl,
                      float* __restrict__ kvq) {
    __shared__ __align__(16) unsigned short ldsA[2][2][PBM * KSTAGE];  // 32 KB
    int tid = threadIdx.x;
    int lane = tid & 63;
    int wv = tid >> 6;                 // 0..3 -> cols [wv*48, +48)
    int fl15 = lane & 15;
    int flh = lane >> 4;               // 0..3
    int rowBase = blockIdx.x * PBM;

    int r_st = tid >> 3;
    int sub  = tid & 7;
    const float* xrow = x + (size_t)(rowBase + r_st) * D_DIM + sub * 8;
    int wb0 = r_st * 256 + ((sub * 16) ^ ((r_st & 7) << 4));
    int wb1 = wb0 + 128;

    const unsigned short* bbh = BPh + (size_t)(wv * 3) * 16384 + lane * 8;
    const unsigned short* bbl = BPl + (size_t)(wv * 3) * 16384 + lane * 8;

    for (int rep = 0; rep < PROJ_REP; ++rep) {
        float z0 = 0.f;
        asm volatile("" : "+v"(z0));
        f32x4 acc[2][3];
        #pragma unroll
        for (int mt = 0; mt < 2; ++mt)
            #pragma unroll
            for (int nt = 0; nt < 3; ++nt) acc[mt][nt] = (f32x4)(z0);

        {
            float4 c0 = *(const float4*)(xrow);
            float4 c1 = *(const float4*)(xrow + 4);
            float4 c2 = *(const float4*)(xrow + 64);
            float4 c3 = *(const float4*)(xrow + 68);
            float v0[8] = {c0.x, c0.y, c0.z, c0.w, c1.x, c1.y, c1.z, c1.w};
            float v1[8] = {c2.x, c2.y, c2.z, c2.w, c3.x, c3.y, c3.z, c3.w};
            short8 h0, l0, h1, l1;
            #pragma unroll
            for (int e = 0; e < 8; ++e) {
                unsigned short hh = f2bf(v0[e]);
                h0[e] = (short)hh; l0[e] = (short)f2bf(v0[e] - bf2f(hh));
                hh = f2bf(v1[e]);
                h1[e] = (short)hh; l1[e] = (short)f2bf(v1[e] - bf2f(hh));
            }
            char* pH = (char*)&ldsA[0][0][0];
            char* pL = (char*)&ldsA[0][1][0];
            *(short8*)(pH + wb0) = h0; *(short8*)(pL + wb0) = l0;
            *(short8*)(pH + wb1) = h1; *(short8*)(pL + wb1) = l1;
        }
        float4 p0 = *(const float4*)(xrow + KSTAGE);
        float4 p1 = *(const float4*)(xrow + KSTAGE + 4);
        float4 p2 = *(const float4*)(xrow + KSTAGE + 64);
        float4 p3 = *(const float4*)(xrow + KSTAGE + 68);
        bar_lgkm();

        #pragma unroll 1
        for (int qt = 0; qt < 8; ++qt) {
            int buf = qt & 1;
            float4 q0, q1, q2, q3;
            if (qt < 6) {
                const float* nx = xrow + (qt + 2) * KSTAGE;
                q0 = *(const float4*)(nx);
                q1 = *(const float4*)(nx + 4);
                q2 = *(const float4*)(nx + 64);
                q3 = *(const float4*)(nx + 68);
            }
            const char* pH = (const char*)&ldsA[buf][0][0];
            const char* pL = (const char*)&ldsA[buf][1][0];
            #pragma unroll
            for (int s = 0; s < 2; ++s) {
                int sg = qt * 2 + s;
                short8 bh[2][3], bl[2][3];
                #pragma unroll
                for (int nt = 0; nt < 3; ++nt)
                    #pragma unroll
                    for (int kk = 0; kk < 2; ++kk) {
                        size_t off = (size_t)nt * 16384 + sg * 1024 + kk * 512;
                        bh[kk][nt] = *(const short8*)(bbh + off);
                        bl[kk][nt] = *(const short8*)(bbl + off);
                    }
                #pragma unroll
                for (int kk = 0; kk < 2; ++kk) {
                    short8 ah[2], al[2];
                    #pragma unroll
                    for (int mt = 0; mt < 2; ++mt) {
                        int row = mt * 16 + fl15;
                        int off = row * 256 + s * 128 +
                                  ((kk * 64 + flh * 16) ^ ((row & 7) << 4));
                        ah[mt] = *(const short8*)(pH + off);
                        al[mt] = *(const short8*)(pL + off);
                    }
                    #pragma unroll
                    for (int mt = 0; mt < 2; ++mt)
                        #pragma unroll
                        for (int nt = 0; nt < 3; ++nt) {
                            acc[mt][nt] = __builtin_amdgcn_mfma_f32_16x16x32_bf16(
                                ah[mt], bh[kk][nt], acc[mt][nt], 0, 0, 0);
                            acc[mt][nt] = __builtin_amdgcn_mfma_f32_16x16x32_bf16(
                                ah[mt], bl[kk][nt], acc[mt][nt], 0, 0, 0);
                            acc[mt][nt] = __builtin_amdgcn_mfma_f32_16x16x32_bf16(
                                al[mt], bh[kk][nt], acc[mt][nt], 0, 0, 0);
                        }
                }
            }
            if (qt < 7) {
                float v0[8] = {p0.x, p0.y, p0.z, p0.w, p1.x, p1.y, p1.z, p1.w};
                float v1[8] = {p2.x, p2.y, p2.z, p2.w, p3.x, p3.y, p3.z, p3.w};
                short8 h0, l0, h1, l1;
                #pragma unroll
                for (int e = 0; e < 8; ++e) {
                    unsigned short hh = f2bf(v0[e]);
                    h0[e] = (short)hh; l0[e] = (short)f2bf(v0[e] - bf2f(hh));
                    hh = f2bf(v1[e]);
                    h1[e] = (short)hh; l1[e] = (short)f2bf(v1[e] - bf2f(hh));
                }
                char* qH = (char*)&ldsA[buf ^ 1][0][0];
                char* qL = (char*)&ldsA[buf ^ 1][1][0];
                *(short8*)(qH + wb0) = h0; *(short8*)(qL + wb0) = l0;
                *(short8*)(qH + wb1) = h1; *(short8*)(qL + wb1) = l1;
            }
            bar_lgkm();
            p0 = q0; p1 = q1; p2 = q2; p3 = q3;
        }

        #pragma unroll
        for (int mt = 0; mt < 2; ++mt)
            #pragma unroll
            for (int nt = 0; nt < 3; ++nt) {
                int col = wv * 48 + nt * 16 + fl15;
                #pragma unroll
                for (int r = 0; r < 4; ++r) {
                    int row = rowBase + mt * 16 + flh * 4 + r;
                    kvq[(size_t)row * 192 + col] = acc[mt][nt][r];
                }
            }
        __syncthreads();
    }
}

// ------------- carry init: S_init[c] = scan of full previous chunk -------------
__global__ __launch_bounds__(256)
void carry_init_kernel(const float* __restrict__ kvq,
                       float* __restrict__ S_init) {
    int blk = blockIdx.x;          // 0..479
    int c   = (blk >> 5) + 1;      // 1..15
    int rem = blk & 31;
    int b   = rem >> 2;
    int iq  = rem & 3;
    int i   = iq * 16 + (threadIdx.x >> 4);
    int j4  = (threadIdx.x & 15) * 4;
    int tp  = (c - 1) * CHUNK_LEN;
    for (int rep = 0; rep < CARRY_REP; ++rep) {
        float z0 = 0.f;
        asm volatile("" : "+v"(z0));
        float4 s4 = {z0, z0, z0, z0};
        #pragma unroll 4
        for (int u = 0; u < CHUNK_LEN; ++u) {
            const float* base = kvq + (size_t)((tp + u) * B_DIM + b) * 192;
            float v = base[64 + i];
            float4 k4 = *(const float4*)(base + j4);
            s4.x = __builtin_fmaf(DECAY, s4.x, v * k4.x);
            s4.y = __builtin_fmaf(DECAY, s4.y, v * k4.y);
            s4.z = __builtin_fmaf(DECAY, s4.z, v * k4.z);
            s4.w = __builtin_fmaf(DECAY, s4.w, v * k4.w);
        }
        *(float4*)&S_init[(((size_t)c * B_DIM + b) * 64 + i) * 64 + j4] = s4;
    }
}

// ------------- scan (R9 structure + repeat) -------------
#define SC_TILE 8
__global__ __launch_bounds__(256)
void scan_kernel(const float* __restrict__ kvq,
                 const float* __restrict__ S_init,
                 const float* __restrict__ S0,
                 float* __restrict__ out,      // [T,B,n]
                 float* __restrict__ S_all) {  // [T+1,B,n,n]
    __shared__ __align__(16) float P[4][SC_TILE][4][20];
    int widL = threadIdx.x >> 6;
    int lane = threadIdx.x & 63;
    int r  = lane >> 4;          // row within wave's 4
    int jq = lane & 15;          // col quad
    int blk = blockIdx.x;
    int c  = blk >> 5;           // 0..15
    int b  = (blk >> 2) & 7;
    int ig = blk & 3;
    int i0 = ig * 16 + widL * 4;
    int i  = i0 + r;

    int pp   = lane >> 1;
    int ur   = pp >> 2;
    int rr   = pp & 3;
    int half = lane & 1;

    for (int rep = 0; rep < SCAN_REP; ++rep) {
        if (c == 0) {
            f32x4 s0v = *(const f32x4*)&S0[((size_t)b * 64 + i) * 64 + jq * 4];
            *(f32x4*)&S_all[(size_t)b * 4096 + (size_t)i * 64 + jq * 4] = s0v;
        }
        f32x4 s = (f32x4)(0.f);
        if (c > 0)
            s = *(const f32x4*)&S_init[(((size_t)c * B_DIM + b) * 64 + i) * 64 + jq * 4];
        asm volatile("" : "+v"(s.x), "+v"(s.y), "+v"(s.z), "+v"(s.w));

        int t0 = c * CHUNK_LEN;
        for (int tb = 0; tb < CHUNK_LEN; tb += SC_TILE) {
            #pragma unroll
            for (int u = 0; u < SC_TILE; ++u) {
                int t = t0 + tb + u;
                const float* base = kvq + (size_t)(t * B_DIM + b) * 192;
                f32x4 k4 = *(const f32x4*)(base + jq * 4);
                f32x4 q4 = *(const f32x4*)(base + 128 + jq * 4);
                float v  = base[64 + i];
                s.x = __builtin_fmaf(DECAY, s.x, v * k4.x);
                s.y = __builtin_fmaf(DECAY, s.y, v * k4.y);
                s.z = __builtin_fmaf(DECAY, s.z, v * k4.z);
                s.w = __builtin_fmaf(DECAY, s.w, v * k4.w);
                __builtin_nontemporal_store(
                    s, (f32x4*)&S_all[((size_t)(t + 1) * B_DIM + b) * 4096 +
                                      (size_t)i * 64 + jq * 4]);
                P[widL][u][r][jq] = s.x * q4.x + s.y * q4.y + s.z * q4.z + s.w * q4.w;
            }
            const float* pr = &P[widL][ur][rr][half * 8];
            f32x4 a0 = *(const f32x4*)pr;
            f32x4 a1 = *(const f32x4*)(pr + 4);
            float acc = (a0.x + a0.y) + (a0.z + a0.w) + (a1.x + a1.y) + (a1.z + a1.w);
            acc += __shfl_xor(acc, 1, 64);
            if (half == 0) {
                int t = t0 + tb + ur;
                float sg = 1.0f / (1.0f + __expf(-acc));
                out[((size_t)t * B_DIM + b) * 64 + i0 + rr] = acc * acc * sg;
            }
        }
    }
}

extern "C" void kernel_launch(void* const* d_in, const int* in_sizes, int n_in,
                              void* d_out, int out_size, void* d_ws, size_t ws_size,
                              hipStream_t stream) {
    const float* x  = (const float*)d_in[0];
    const float* S0 = (const float*)d_in[1];
    const float* Wk = (const float*)d_in[2];
    const float* Wv = (const float*)d_in[3];
    const float* Wq = (const float*)d_in[4];
    const float* uk = (const float*)d_in[5];
    const float* uv = (const float*)d_in[6];

    float* out   = (float*)d_out;                              // [T,B,n]
    float* S_all = out + (size_t)T_DIM * B_DIM * N_DIM;        // [T+1,B,n,n]

    float* ws    = (float*)d_ws;
    float* scale = ws;                                   // 2 floats (pad 64)
    float* kvq   = ws + 64;                              // 16384*192
    unsigned short* BPh = (unsigned short*)(kvq + (size_t)16384 * 192);  // 192*1024
    unsigned short* BPl = BPh + (size_t)192 * D_DIM;
    float* S_init = (float*)(BPl + (size_t)192 * D_DIM); // 16*8*64*64 floats

    spectral_kernel<<<2, 1024, 0, stream>>>(Wk, Wv, uk, uv, scale);
    build_wt_kernel<<<192, 256, 0, stream>>>(Wk, Wv, Wq, scale, BPh, BPl);
    proj_mfma_kernel<<<T_DIM * B_DIM / PBM, 256, 0, stream>>>(x, BPh, BPl, kvq);
    carry_init_kernel<<<(NCHUNK - 1) * 32, 256, 0, stream>>>(kvq, S_init);
    scan_kernel<<<NCHUNK * B_DIM * 4, 256, 0, stream>>>(kvq, S_init, S0, out, S_all);
}

// Round 11
// 123.029 us; speedup vs baseline: 13.0013x; 13.0013x over previous
//
#include <hip/hip_runtime.h>
#include <math.h>

#define T_DIM 2048
#define B_DIM 8
#define D_DIM 1024
#define N_DIM 64
#define NCHUNK 16
#define CHUNK_LEN 128              // T_DIM / NCHUNK
#define DECAY 0.9f
#define EPS 1e-8f
#define RADIUS 0.5f

typedef __attribute__((ext_vector_type(8))) short short8;   // bf16x8 MFMA frag
typedef __attribute__((ext_vector_type(4))) float f32x4;

static __device__ __forceinline__ unsigned short f2bf(float f) {
    unsigned u = __float_as_uint(f);
    u += 0x7FFFu + ((u >> 16) & 1u);          // RNE
    return (unsigned short)(u >> 16);
}
static __device__ __forceinline__ float bf2f(unsigned short h) {
    return __uint_as_float(((unsigned)h) << 16);
}

// counted barrier: flush LDS writes, sync waves, do NOT drain vmcnt (T4)
static __device__ __forceinline__ void bar_lgkm() {
    asm volatile("s_waitcnt lgkmcnt(0)" ::: "memory");
    __builtin_amdgcn_s_barrier();
    asm volatile("" ::: "memory");
}

// ---------------- Gram matrix: G[mat] = W W^T (64x64), 128 blocks ----------------
__global__ __launch_bounds__(256)
void gram_kernel(const float* __restrict__ Wk, const float* __restrict__ Wv,
                 float* __restrict__ G) {
    int mat = blockIdx.x >> 6;
    int i   = blockIdx.x & 63;
    const float* W = mat ? Wv : Wk;
    __shared__ float wsr[D_DIM];
    __shared__ float part[4][64];
    int tid = threadIdx.x;
    *(float4*)&wsr[tid * 4] = *(const float4*)(W + (size_t)i * D_DIM + tid * 4);
    __syncthreads();
    int j = tid & 63, p = tid >> 6;
    const float* wj = W + (size_t)j * D_DIM + p * 256;
    const float* wp = wsr + p * 256;
    float acc = 0.f;
    #pragma unroll 16
    for (int k = 0; k < 256; k += 4) {
        float4 a = *(const float4*)(wj + k);
        float4 b = *(const float4*)(wp + k);
        acc += a.x * b.x + a.y * b.y + a.z * b.z + a.w * b.w;
    }
    part[p][j] = acc;
    __syncthreads();
    if (tid < 64)
        G[((size_t)mat * 64 + i) * 64 + tid] =
            part[0][tid] + part[1][tid] + part[2][tid] + part[3][tid];
}

// ---------------- power iteration in G-space (exact algebra incl. eps) ----------------
// t = G u = W(W^T u); ||v_raw|| = sqrt(u.t); u_raw = t/(nv+eps); u' = u_raw/(nu+eps)
// sigma = u_hat . (W v_hat) = ||u_raw||^2 / (||u_raw|| + eps)
__global__ __launch_bounds__(64)
void power_kernel(const float* __restrict__ G, const float* __restrict__ uk,
                  const float* __restrict__ uv, float* __restrict__ scale_out) {
    __shared__ float Gs[64][65];
    __shared__ float us[64];
    int mat = blockIdx.x;
    int i = threadIdx.x;
    #pragma unroll 8
    for (int r = 0; r < 64; ++r)
        Gs[r][i] = G[((size_t)mat * 64 + r) * 64 + i];
    us[i] = (mat ? uv : uk)[i];
    __syncthreads();
    float sigma = 0.f;
    for (int it = 0; it < 3; ++it) {
        float t = 0.f;
        #pragma unroll
        for (int jj = 0; jj < 64; ++jj)
            t += Gs[i][jj] * us[jj];
        float nv2 = us[i] * t;
        #pragma unroll
        for (int o = 32; o > 0; o >>= 1) nv2 += __shfl_xor(nv2, o, 64);
        float nv = sqrtf(fmaxf(nv2, 0.f));
        float ur = t / (nv + EPS);
        float nu2 = ur * ur;
        #pragma unroll
        for (int o = 32; o > 0; o >>= 1) nu2 += __shfl_xor(nu2, o, 64);
        float nu = sqrtf(nu2);
        if (it == 2) sigma = nu2 / (nu + EPS);
        __syncthreads();
        us[i] = ur / (nu + EPS);
        __syncthreads();
    }
    if (i == 0) scale_out[mat] = RADIUS / (sigma + EPS);
}

// ------- build bf16 hi/lo pack, PACK-LINEAR (coalesced writes) -------
// chunk m in group g: m = s*128 + kk*64 + flh*16 + fl  <=>  pack idx = g*16384 + m*8 + e
// k = s*64 + kk*32 + flh*8 + e; c = g*16 + fl  (verified inverse of proven layout)
__global__ __launch_bounds__(256)
void build_wt_kernel(const float* __restrict__ Wk, const float* __restrict__ Wv,
                     const float* __restrict__ Wq, const float* __restrict__ scale,
                     unsigned short* __restrict__ BPh, unsigned short* __restrict__ BPl) {
    int bid = blockIdx.x;          // 96 blocks
    int g   = bid >> 3;            // 0..11
    int sub = bid & 7;
    int m   = sub * 256 + threadIdx.x;   // chunk id 0..2047
    int gm  = g >> 2;              // matrix: 0=k,1=v,2=q
    const float* W = (gm == 0) ? Wk : (gm == 1) ? Wv : Wq;
    float sc = (gm == 0) ? scale[0] : (gm == 1) ? scale[1] : 1.0f;
    int s   = m >> 7;
    int kk  = (m >> 6) & 1;
    int flh = (m >> 4) & 3;
    int fl  = m & 15;
    int row = (g & 3) * 16 + fl;
    int k0  = s * 64 + kk * 32 + flh * 8;
    const float* src = W + (size_t)row * D_DIM + k0;
    float4 a = *(const float4*)src;
    float4 b = *(const float4*)(src + 4);
    float v[8] = {a.x, a.y, a.z, a.w, b.x, b.y, b.z, b.w};
    short8 hv, lv;
    #pragma unroll
    for (int e = 0; e < 8; ++e) {
        float val = v[e] * sc;
        unsigned short hh = f2bf(val);
        hv[e] = (short)hh;
        lv[e] = (short)f2bf(val - bf2f(hh));
    }
    size_t o = (size_t)g * 16384 + (size_t)m * 8;
    *(short8*)(BPh + o) = hv;
    *(short8*)(BPl + o) = lv;
}

// ------------- projections via split-bf16 MFMA (R9 structure) -------------
#define PBM 32
#define KSTAGE 128
__global__ __launch_bounds__(256)
void proj_mfma_kernel(const float* __restrict__ x,
                      const unsigned short* __restrict__ BPh,
                      const unsigned short* __restrict__ BPl,
                      float* __restrict__ kvq) {
    __shared__ __align__(16) unsigned short ldsA[2][2][PBM * KSTAGE];  // 32 KB
    int tid = threadIdx.x;
    int lane = tid & 63;
    int wv = tid >> 6;                 // 0..3 -> cols [wv*48, +48)
    int fl15 = lane & 15;
    int flh = lane >> 4;               // 0..3
    int rowBase = blockIdx.x * PBM;

    int r_st = tid >> 3;
    int sub  = tid & 7;
    const float* xrow = x + (size_t)(rowBase + r_st) * D_DIM + sub * 8;
    int wb0 = r_st * 256 + ((sub * 16) ^ ((r_st & 7) << 4));
    int wb1 = wb0 + 128;

    const unsigned short* bbh = BPh + (size_t)(wv * 3) * 16384 + lane * 8;
    const unsigned short* bbl = BPl + (size_t)(wv * 3) * 16384 + lane * 8;

    f32x4 acc[2][3];
    #pragma unroll
    for (int mt = 0; mt < 2; ++mt)
        #pragma unroll
        for (int nt = 0; nt < 3; ++nt) acc[mt][nt] = (f32x4)(0.f);

    {
        float4 c0 = *(const float4*)(xrow);
        float4 c1 = *(const float4*)(xrow + 4);
        float4 c2 = *(const float4*)(xrow + 64);
        float4 c3 = *(const float4*)(xrow + 68);
        float v0[8] = {c0.x, c0.y, c0.z, c0.w, c1.x, c1.y, c1.z, c1.w};
        float v1[8] = {c2.x, c2.y, c2.z, c2.w, c3.x, c3.y, c3.z, c3.w};
        short8 h0, l0, h1, l1;
        #pragma unroll
        for (int e = 0; e < 8; ++e) {
            unsigned short hh = f2bf(v0[e]);
            h0[e] = (short)hh; l0[e] = (short)f2bf(v0[e] - bf2f(hh));
            hh = f2bf(v1[e]);
            h1[e] = (short)hh; l1[e] = (short)f2bf(v1[e] - bf2f(hh));
        }
        char* pH = (char*)&ldsA[0][0][0];
        char* pL = (char*)&ldsA[0][1][0];
        *(short8*)(pH + wb0) = h0; *(short8*)(pL + wb0) = l0;
        *(short8*)(pH + wb1) = h1; *(short8*)(pL + wb1) = l1;
    }
    float4 p0 = *(const float4*)(xrow + KSTAGE);
    float4 p1 = *(const float4*)(xrow + KSTAGE + 4);
    float4 p2 = *(const float4*)(xrow + KSTAGE + 64);
    float4 p3 = *(const float4*)(xrow + KSTAGE + 68);
    bar_lgkm();

    #pragma unroll 1
    for (int qt = 0; qt < 8; ++qt) {
        int buf = qt & 1;
        float4 q0, q1, q2, q3;
        if (qt < 6) {
            const float* nx = xrow + (qt + 2) * KSTAGE;
            q0 = *(const float4*)(nx);
            q1 = *(const float4*)(nx + 4);
            q2 = *(const float4*)(nx + 64);
            q3 = *(const float4*)(nx + 68);
        }
        const char* pH = (const char*)&ldsA[buf][0][0];
        const char* pL = (const char*)&ldsA[buf][1][0];
        #pragma unroll
        for (int s = 0; s < 2; ++s) {
            int sg = qt * 2 + s;
            short8 bh[2][3], bl[2][3];
            #pragma unroll
            for (int nt = 0; nt < 3; ++nt)
                #pragma unroll
                for (int kk = 0; kk < 2; ++kk) {
                    size_t off = (size_t)nt * 16384 + sg * 1024 + kk * 512;
                    bh[kk][nt] = *(const short8*)(bbh + off);
                    bl[kk][nt] = *(const short8*)(bbl + off);
                }
            #pragma unroll
            for (int kk = 0; kk < 2; ++kk) {
                short8 ah[2], al[2];
                #pragma unroll
                for (int mt = 0; mt < 2; ++mt) {
                    int row = mt * 16 + fl15;
                    int off = row * 256 + s * 128 +
                              ((kk * 64 + flh * 16) ^ ((row & 7) << 4));
                    ah[mt] = *(const short8*)(pH + off);
                    al[mt] = *(const short8*)(pL + off);
                }
                #pragma unroll
                for (int mt = 0; mt < 2; ++mt)
                    #pragma unroll
                    for (int nt = 0; nt < 3; ++nt) {
                        acc[mt][nt] = __builtin_amdgcn_mfma_f32_16x16x32_bf16(
                            ah[mt], bh[kk][nt], acc[mt][nt], 0, 0, 0);
                        acc[mt][nt] = __builtin_amdgcn_mfma_f32_16x16x32_bf16(
                            ah[mt], bl[kk][nt], acc[mt][nt], 0, 0, 0);
                        acc[mt][nt] = __builtin_amdgcn_mfma_f32_16x16x32_bf16(
                            al[mt], bh[kk][nt], acc[mt][nt], 0, 0, 0);
                    }
            }
        }
        if (qt < 7) {
            float v0[8] = {p0.x, p0.y, p0.z, p0.w, p1.x, p1.y, p1.z, p1.w};
            float v1[8] = {p2.x, p2.y, p2.z, p2.w, p3.x, p3.y, p3.z, p3.w};
            short8 h0, l0, h1, l1;
            #pragma unroll
            for (int e = 0; e < 8; ++e) {
                unsigned short hh = f2bf(v0[e]);
                h0[e] = (short)hh; l0[e] = (short)f2bf(v0[e] - bf2f(hh));
                hh = f2bf(v1[e]);
                h1[e] = (short)hh; l1[e] = (short)f2bf(v1[e] - bf2f(hh));
            }
            char* qH = (char*)&ldsA[buf ^ 1][0][0];
            char* qL = (char*)&ldsA[buf ^ 1][1][0];
            *(short8*)(qH + wb0) = h0; *(short8*)(qL + wb0) = l0;
            *(short8*)(qH + wb1) = h1; *(short8*)(qL + wb1) = l1;
        }
        bar_lgkm();
        p0 = q0; p1 = q1; p2 = q2; p3 = q3;
    }

    #pragma unroll
    for (int mt = 0; mt < 2; ++mt)
        #pragma unroll
        for (int nt = 0; nt < 3; ++nt) {
            int col = wv * 48 + nt * 16 + fl15;
            #pragma unroll
            for (int r = 0; r < 4; ++r) {
                int row = rowBase + mt * 16 + flh * 4 + r;
                kvq[(size_t)row * 192 + col] = acc[mt][nt][r];
            }
        }
}

// ------------- carry init: S_init[c] = scan of full previous chunk -------------
__global__ __launch_bounds__(256)
void carry_init_kernel(const float* __restrict__ kvq,
                       float* __restrict__ S_init) {
    int blk = blockIdx.x;          // 0..479
    int c   = (blk >> 5) + 1;      // 1..15
    int rem = blk & 31;
    int b   = rem >> 2;
    int iq  = rem & 3;
    int i   = iq * 16 + (threadIdx.x >> 4);
    int j4  = (threadIdx.x & 15) * 4;
    int tp  = (c - 1) * CHUNK_LEN;
    float4 s4 = {0.f, 0.f, 0.f, 0.f};
    #pragma unroll 4
    for (int u = 0; u < CHUNK_LEN; ++u) {
        const float* base = kvq + (size_t)((tp + u) * B_DIM + b) * 192;
        float v = base[64 + i];
        float4 k4 = *(const float4*)(base + j4);
        s4.x = __builtin_fmaf(DECAY, s4.x, v * k4.x);
        s4.y = __builtin_fmaf(DECAY, s4.y, v * k4.y);
        s4.z = __builtin_fmaf(DECAY, s4.z, v * k4.z);
        s4.w = __builtin_fmaf(DECAY, s4.w, v * k4.w);
    }
    *(float4*)&S_init[(((size_t)c * B_DIM + b) * 64 + i) * 64 + j4] = s4;
}

// ------------- scan: lane = (r,jq) holds S[i0+r][4jq..+3]; dwordx4 NT stores -------------
#define SC_TILE 8
__global__ __launch_bounds__(256)
void scan_kernel(const float* __restrict__ kvq,
                 const float* __restrict__ S_init,
                 const float* __restrict__ S0,
                 float* __restrict__ out,      // [T,B,n]
                 float* __restrict__ S_all) {  // [T+1,B,n,n]
    __shared__ __align__(16) float P[4][SC_TILE][4][20];
    int widL = threadIdx.x >> 6;
    int lane = threadIdx.x & 63;
    int r  = lane >> 4;          // row within wave's 4
    int jq = lane & 15;          // col quad
    int blk = blockIdx.x;
    int c  = blk >> 5;           // 0..15
    int b  = (blk >> 2) & 7;
    int ig = blk & 3;
    int i0 = ig * 16 + widL * 4;
    int i  = i0 + r;

    int pp   = lane >> 1;
    int ur   = pp >> 2;
    int rr   = pp & 3;
    int half = lane & 1;

    if (c == 0) {
        f32x4 s0v = *(const f32x4*)&S0[((size_t)b * 64 + i) * 64 + jq * 4];
        *(f32x4*)&S_all[(size_t)b * 4096 + (size_t)i * 64 + jq * 4] = s0v;
    }

    f32x4 s = (f32x4)(0.f);
    if (c > 0)
        s = *(const f32x4*)&S_init[(((size_t)c * B_DIM + b) * 64 + i) * 64 + jq * 4];

    int t0 = c * CHUNK_LEN;
    for (int tb = 0; tb < CHUNK_LEN; tb += SC_TILE) {
        #pragma unroll
        for (int u = 0; u < SC_TILE; ++u) {
            int t = t0 + tb + u;
            const float* base = kvq + (size_t)(t * B_DIM + b) * 192;
            f32x4 k4 = *(const f32x4*)(base + jq * 4);
            f32x4 q4 = *(const f32x4*)(base + 128 + jq * 4);
            float v  = base[64 + i];
            s.x = __builtin_fmaf(DECAY, s.x, v * k4.x);
            s.y = __builtin_fmaf(DECAY, s.y, v * k4.y);
            s.z = __builtin_fmaf(DECAY, s.z, v * k4.z);
            s.w = __builtin_fmaf(DECAY, s.w, v * k4.w);
            __builtin_nontemporal_store(
                s, (f32x4*)&S_all[((size_t)(t + 1) * B_DIM + b) * 4096 +
                                  (size_t)i * 64 + jq * 4]);
            P[widL][u][r][jq] = s.x * q4.x + s.y * q4.y + s.z * q4.z + s.w * q4.w;
        }
        const float* pr = &P[widL][ur][rr][half * 8];
        f32x4 a0 = *(const f32x4*)pr;
        f32x4 a1 = *(const f32x4*)(pr + 4);
        float acc = (a0.x + a0.y) + (a0.z + a0.w) + (a1.x + a1.y) + (a1.z + a1.w);
        acc += __shfl_xor(acc, 1, 64);
        if (half == 0) {
            int t = t0 + tb + ur;
            float sg = 1.0f / (1.0f + __expf(-acc));
            out[((size_t)t * B_DIM + b) * 64 + i0 + rr] = acc * acc * sg;
        }
    }
}

extern "C" void kernel_launch(void* const* d_in, const int* in_sizes, int n_in,
                              void* d_out, int out_size, void* d_ws, size_t ws_size,
                              hipStream_t stream) {
    const float* x  = (const float*)d_in[0];
    const float* S0 = (const float*)d_in[1];
    const float* Wk = (const float*)d_in[2];
    const float* Wv = (const float*)d_in[3];
    const float* Wq = (const float*)d_in[4];
    const float* uk = (const float*)d_in[5];
    const float* uv = (const float*)d_in[6];

    float* out   = (float*)d_out;                              // [T,B,n]
    float* S_all = out + (size_t)T_DIM * B_DIM * N_DIM;        // [T+1,B,n,n]

    float* ws    = (float*)d_ws;
    float* scale = ws;                                   // 2 floats (pad 64)
    float* kvq   = ws + 64;                              // 16384*192
    unsigned short* BPh = (unsigned short*)(kvq + (size_t)16384 * 192);  // 192*1024
    unsigned short* BPl = BPh + (size_t)192 * D_DIM;
    float* S_init = (float*)(BPl + (size_t)192 * D_DIM); // 16*8*64*64 floats
    float* G      = S_init + (size_t)NCHUNK * 32768;     // 2*64*64 floats

    gram_kernel<<<128, 256, 0, stream>>>(Wk, Wv, G);
    power_kernel<<<2, 64, 0, stream>>>(G, uk, uv, scale);
    build_wt_kernel<<<96, 256, 0, stream>>>(Wk, Wv, Wq, scale, BPh, BPl);
    proj_mfma_kernel<<<T_DIM * B_DIM / PBM, 256, 0, stream>>>(x, BPh, BPl, kvq);
    carry_init_kernel<<<(NCHUNK - 1) * 32, 256, 0, stream>>>(kvq, S_init);
    scan_kernel<<<NCHUNK * B_DIM * 4, 256, 0, stream>>>(kvq, S_init, S0, out, S_all);
}

// Round 12
// 120.128 us; speedup vs baseline: 13.3154x; 1.0242x over previous
//
#include <hip/hip_runtime.h>
#include <math.h>

#define T_DIM 2048
#define B_DIM 8
#define D_DIM 1024
#define N_DIM 64
#define NCHUNK 16
#define CHUNK_LEN 128              // T_DIM / NCHUNK
#define DECAY 0.9f
#define EPS 1e-8f
#define RADIUS 0.5f

typedef __attribute__((ext_vector_type(8))) short short8;   // bf16x8 MFMA frag
typedef __attribute__((ext_vector_type(4))) float f32x4;

static __device__ __forceinline__ unsigned short f2bf(float f) {
    unsigned u = __float_as_uint(f);
    u += 0x7FFFu + ((u >> 16) & 1u);          // RNE
    return (unsigned short)(u >> 16);
}
static __device__ __forceinline__ float bf2f(unsigned short h) {
    return __uint_as_float(((unsigned)h) << 16);
}

// counted barrier: flush LDS writes, sync waves, do NOT drain vmcnt (T4)
static __device__ __forceinline__ void bar_lgkm() {
    asm volatile("s_waitcnt lgkmcnt(0)" ::: "memory");
    __builtin_amdgcn_s_barrier();
    asm volatile("" ::: "memory");
}

// ---------------- Gram matrix: G[mat] = W W^T (64x64), 128 blocks ----------------
__global__ __launch_bounds__(256)
void gram_kernel(const float* __restrict__ Wk, const float* __restrict__ Wv,
                 float* __restrict__ G) {
    int mat = blockIdx.x >> 6;
    int i   = blockIdx.x & 63;
    const float* W = mat ? Wv : Wk;
    __shared__ float wsr[D_DIM];
    __shared__ float part[4][64];
    int tid = threadIdx.x;
    *(float4*)&wsr[tid * 4] = *(const float4*)(W + (size_t)i * D_DIM + tid * 4);
    __syncthreads();
    int j = tid & 63, p = tid >> 6;
    const float* wj = W + (size_t)j * D_DIM + p * 256;
    const float* wp = wsr + p * 256;
    float acc = 0.f;
    #pragma unroll 16
    for (int k = 0; k < 256; k += 4) {
        float4 a = *(const float4*)(wj + k);
        float4 b = *(const float4*)(wp + k);
        acc += a.x * b.x + a.y * b.y + a.z * b.z + a.w * b.w;
    }
    part[p][j] = acc;
    __syncthreads();
    if (tid < 64)
        G[((size_t)mat * 64 + i) * 64 + tid] =
            part[0][tid] + part[1][tid] + part[2][tid] + part[3][tid];
}

// ---------------- power iteration in G-space (exact algebra incl. eps) ----------------
__global__ __launch_bounds__(64)
void power_kernel(const float* __restrict__ G, const float* __restrict__ uk,
                  const float* __restrict__ uv, float* __restrict__ scale_out) {
    __shared__ float Gs[64][65];
    __shared__ float us[64];
    int mat = blockIdx.x;
    int i = threadIdx.x;
    #pragma unroll 8
    for (int r = 0; r < 64; ++r)
        Gs[r][i] = G[((size_t)mat * 64 + r) * 64 + i];
    us[i] = (mat ? uv : uk)[i];
    __syncthreads();
    float sigma = 0.f;
    for (int it = 0; it < 3; ++it) {
        float t = 0.f;
        #pragma unroll
        for (int jj = 0; jj < 64; ++jj)
            t += Gs[i][jj] * us[jj];
        float nv2 = us[i] * t;
        #pragma unroll
        for (int o = 32; o > 0; o >>= 1) nv2 += __shfl_xor(nv2, o, 64);
        float nv = sqrtf(fmaxf(nv2, 0.f));
        float ur = t / (nv + EPS);
        float nu2 = ur * ur;
        #pragma unroll
        for (int o = 32; o > 0; o >>= 1) nu2 += __shfl_xor(nu2, o, 64);
        float nu = sqrtf(nu2);
        if (it == 2) sigma = nu2 / (nu + EPS);
        __syncthreads();
        us[i] = ur / (nu + EPS);
        __syncthreads();
    }
    if (i == 0) scale_out[mat] = RADIUS / (sigma + EPS);
}

// ------- build bf16 hi/lo pack, PACK-LINEAR (coalesced writes) -------
__global__ __launch_bounds__(256)
void build_wt_kernel(const float* __restrict__ Wk, const float* __restrict__ Wv,
                     const float* __restrict__ Wq, const float* __restrict__ scale,
                     unsigned short* __restrict__ BPh, unsigned short* __restrict__ BPl) {
    int bid = blockIdx.x;          // 96 blocks
    int g   = bid >> 3;            // 0..11
    int sub = bid & 7;
    int m   = sub * 256 + threadIdx.x;   // chunk id 0..2047
    int gm  = g >> 2;              // matrix: 0=k,1=v,2=q
    const float* W = (gm == 0) ? Wk : (gm == 1) ? Wv : Wq;
    float sc = (gm == 0) ? scale[0] : (gm == 1) ? scale[1] : 1.0f;
    int s   = m >> 7;
    int kk  = (m >> 6) & 1;
    int flh = (m >> 4) & 3;
    int fl  = m & 15;
    int row = (g & 3) * 16 + fl;
    int k0  = s * 64 + kk * 32 + flh * 8;
    const float* src = W + (size_t)row * D_DIM + k0;
    float4 a = *(const float4*)src;
    float4 b = *(const float4*)(src + 4);
    float v[8] = {a.x, a.y, a.z, a.w, b.x, b.y, b.z, b.w};
    short8 hv, lv;
    #pragma unroll
    for (int e = 0; e < 8; ++e) {
        float val = v[e] * sc;
        unsigned short hh = f2bf(val);
        hv[e] = (short)hh;
        lv[e] = (short)f2bf(val - bf2f(hh));
    }
    size_t o = (size_t)g * 16384 + (size_t)m * 8;
    *(short8*)(BPh + o) = hv;
    *(short8*)(BPl + o) = lv;
}

// ------------- projections: x as SINGLE bf16 plane, W hi/lo (2 MFMAs/triple) -------------
#define PBM 32
#define KSTAGE 128
__global__ __launch_bounds__(256)
void proj_mfma_kernel(const float* __restrict__ x,
                      const unsigned short* __restrict__ BPh,
                      const unsigned short* __restrict__ BPl,
                      float* __restrict__ kvq) {
    __shared__ __align__(16) unsigned short ldsA[2][PBM * KSTAGE];  // 16 KB
    int tid = threadIdx.x;
    int lane = tid & 63;
    int wv = tid >> 6;                 // 0..3 -> cols [wv*48, +48)
    int fl15 = lane & 15;
    int flh = lane >> 4;               // 0..3
    int rowBase = blockIdx.x * PBM;

    int r_st = tid >> 3;
    int sub  = tid & 7;
    const float* xrow = x + (size_t)(rowBase + r_st) * D_DIM + sub * 8;
    int wb0 = r_st * 256 + ((sub * 16) ^ ((r_st & 7) << 4));
    int wb1 = wb0 + 128;

    const unsigned short* bbh = BPh + (size_t)(wv * 3) * 16384 + lane * 8;
    const unsigned short* bbl = BPl + (size_t)(wv * 3) * 16384 + lane * 8;

    f32x4 acc[2][3];
    #pragma unroll
    for (int mt = 0; mt < 2; ++mt)
        #pragma unroll
        for (int nt = 0; nt < 3; ++nt) acc[mt][nt] = (f32x4)(0.f);

    // prologue: stage 0 -> buf0 (single bf16 plane); stage 1 -> regs p*
    {
        float4 c0 = *(const float4*)(xrow);
        float4 c1 = *(const float4*)(xrow + 4);
        float4 c2 = *(const float4*)(xrow + 64);
        float4 c3 = *(const float4*)(xrow + 68);
        float v0[8] = {c0.x, c0.y, c0.z, c0.w, c1.x, c1.y, c1.z, c1.w};
        float v1[8] = {c2.x, c2.y, c2.z, c2.w, c3.x, c3.y, c3.z, c3.w};
        short8 h0, h1;
        #pragma unroll
        for (int e = 0; e < 8; ++e) {
            h0[e] = (short)f2bf(v0[e]);
            h1[e] = (short)f2bf(v1[e]);
        }
        char* pH = (char*)&ldsA[0][0];
        *(short8*)(pH + wb0) = h0;
        *(short8*)(pH + wb1) = h1;
    }
    float4 p0 = *(const float4*)(xrow + KSTAGE);
    float4 p1 = *(const float4*)(xrow + KSTAGE + 4);
    float4 p2 = *(const float4*)(xrow + KSTAGE + 64);
    float4 p3 = *(const float4*)(xrow + KSTAGE + 68);
    bar_lgkm();

    #pragma unroll 1
    for (int qt = 0; qt < 8; ++qt) {
        int buf = qt & 1;
        float4 q0, q1, q2, q3;
        if (qt < 6) {
            const float* nx = xrow + (qt + 2) * KSTAGE;
            q0 = *(const float4*)(nx);
            q1 = *(const float4*)(nx + 4);
            q2 = *(const float4*)(nx + 64);
            q3 = *(const float4*)(nx + 68);
        }
        const char* pH = (const char*)&ldsA[buf][0];
        #pragma unroll
        for (int s = 0; s < 2; ++s) {
            int sg = qt * 2 + s;
            short8 bh[2][3], bl[2][3];
            #pragma unroll
            for (int nt = 0; nt < 3; ++nt)
                #pragma unroll
                for (int kk = 0; kk < 2; ++kk) {
                    size_t off = (size_t)nt * 16384 + sg * 1024 + kk * 512;
                    bh[kk][nt] = *(const short8*)(bbh + off);
                    bl[kk][nt] = *(const short8*)(bbl + off);
                }
            #pragma unroll
            for (int kk = 0; kk < 2; ++kk) {
                short8 ah[2];
                #pragma unroll
                for (int mt = 0; mt < 2; ++mt) {
                    int row = mt * 16 + fl15;
                    int off = row * 256 + s * 128 +
                              ((kk * 64 + flh * 16) ^ ((row & 7) << 4));
                    ah[mt] = *(const short8*)(pH + off);
                }
                #pragma unroll
                for (int mt = 0; mt < 2; ++mt)
                    #pragma unroll
                    for (int nt = 0; nt < 3; ++nt) {
                        acc[mt][nt] = __builtin_amdgcn_mfma_f32_16x16x32_bf16(
                            ah[mt], bh[kk][nt], acc[mt][nt], 0, 0, 0);
                        acc[mt][nt] = __builtin_amdgcn_mfma_f32_16x16x32_bf16(
                            ah[mt], bl[kk][nt], acc[mt][nt], 0, 0, 0);
                    }
            }
        }
        if (qt < 7) {
            float v0[8] = {p0.x, p0.y, p0.z, p0.w, p1.x, p1.y, p1.z, p1.w};
            float v1[8] = {p2.x, p2.y, p2.z, p2.w, p3.x, p3.y, p3.z, p3.w};
            short8 h0, h1;
            #pragma unroll
            for (int e = 0; e < 8; ++e) {
                h0[e] = (short)f2bf(v0[e]);
                h1[e] = (short)f2bf(v1[e]);
            }
            char* qH = (char*)&ldsA[buf ^ 1][0];
            *(short8*)(qH + wb0) = h0;
            *(short8*)(qH + wb1) = h1;
        }
        bar_lgkm();
        p0 = q0; p1 = q1; p2 = q2; p3 = q3;
    }

    // epilogue: C/D layout col=lane&15, row=(lane>>4)*4+reg  [m89]
    #pragma unroll
    for (int mt = 0; mt < 2; ++mt)
        #pragma unroll
        for (int nt = 0; nt < 3; ++nt) {
            int col = wv * 48 + nt * 16 + fl15;
            #pragma unroll
            for (int r = 0; r < 4; ++r) {
                int row = rowBase + mt * 16 + flh * 4 + r;
                kvq[(size_t)row * 192 + col] = acc[mt][nt][r];
            }
        }
}

// ------------- carry init: S_init[c] = scan of full previous chunk -------------
__global__ __launch_bounds__(256)
void carry_init_kernel(const float* __restrict__ kvq,
                       float* __restrict__ S_init) {
    int blk = blockIdx.x;          // 0..479
    int c   = (blk >> 5) + 1;      // 1..15
    int rem = blk & 31;
    int b   = rem >> 2;
    int iq  = rem & 3;
    int i   = iq * 16 + (threadIdx.x >> 4);
    int j4  = (threadIdx.x & 15) * 4;
    int tp  = (c - 1) * CHUNK_LEN;
    float4 s4 = {0.f, 0.f, 0.f, 0.f};
    #pragma unroll 4
    for (int u = 0; u < CHUNK_LEN; ++u) {
        const float* base = kvq + (size_t)((tp + u) * B_DIM + b) * 192;
        float v = base[64 + i];
        float4 k4 = *(const float4*)(base + j4);
        s4.x = __builtin_fmaf(DECAY, s4.x, v * k4.x);
        s4.y = __builtin_fmaf(DECAY, s4.y, v * k4.y);
        s4.z = __builtin_fmaf(DECAY, s4.z, v * k4.z);
        s4.w = __builtin_fmaf(DECAY, s4.w, v * k4.w);
    }
    *(float4*)&S_init[(((size_t)c * B_DIM + b) * 64 + i) * 64 + j4] = s4;
}

// ------------- scan: lane = (r,jq) holds S[i0+r][4jq..+3]; dwordx4 NT stores -------------
#define SC_TILE 8
__global__ __launch_bounds__(256)
void scan_kernel(const float* __restrict__ kvq,
                 const float* __restrict__ S_init,
                 const float* __restrict__ S0,
                 float* __restrict__ out,      // [T,B,n]
                 float* __restrict__ S_all) {  // [T+1,B,n,n]
    __shared__ __align__(16) float P[4][SC_TILE][4][20];
    int widL = threadIdx.x >> 6;
    int lane = threadIdx.x & 63;
    int r  = lane >> 4;          // row within wave's 4
    int jq = lane & 15;          // col quad
    int blk = blockIdx.x;
    int c  = blk >> 5;           // 0..15
    int b  = (blk >> 2) & 7;
    int ig = blk & 3;
    int i0 = ig * 16 + widL * 4;
    int i  = i0 + r;

    int pp   = lane >> 1;
    int ur   = pp >> 2;
    int rr   = pp & 3;
    int half = lane & 1;

    if (c == 0) {
        f32x4 s0v = *(const f32x4*)&S0[((size_t)b * 64 + i) * 64 + jq * 4];
        *(f32x4*)&S_all[(size_t)b * 4096 + (size_t)i * 64 + jq * 4] = s0v;
    }

    f32x4 s = (f32x4)(0.f);
    if (c > 0)
        s = *(const f32x4*)&S_init[(((size_t)c * B_DIM + b) * 64 + i) * 64 + jq * 4];

    int t0 = c * CHUNK_LEN;
    for (int tb = 0; tb < CHUNK_LEN; tb += SC_TILE) {
        #pragma unroll
        for (int u = 0; u < SC_TILE; ++u) {
            int t = t0 + tb + u;
            const float* base = kvq + (size_t)(t * B_DIM + b) * 192;
            f32x4 k4 = *(const f32x4*)(base + jq * 4);
            f32x4 q4 = *(const f32x4*)(base + 128 + jq * 4);
            float v  = base[64 + i];
            s.x = __builtin_fmaf(DECAY, s.x, v * k4.x);
            s.y = __builtin_fmaf(DECAY, s.y, v * k4.y);
            s.z = __builtin_fmaf(DECAY, s.z, v * k4.z);
            s.w = __builtin_fmaf(DECAY, s.w, v * k4.w);
            __builtin_nontemporal_store(
                s, (f32x4*)&S_all[((size_t)(t + 1) * B_DIM + b) * 4096 +
                                  (size_t)i * 64 + jq * 4]);
            P[widL][u][r][jq] = s.x * q4.x + s.y * q4.y + s.z * q4.z + s.w * q4.w;
        }
        const float* pr = &P[widL][ur][rr][half * 8];
        f32x4 a0 = *(const f32x4*)pr;
        f32x4 a1 = *(const f32x4*)(pr + 4);
        float acc = (a0.x + a0.y) + (a0.z + a0.w) + (a1.x + a1.y) + (a1.z + a1.w);
        acc += __shfl_xor(acc, 1, 64);
        if (half == 0) {
            int t = t0 + tb + ur;
            float sg = 1.0f / (1.0f + __expf(-acc));
            out[((size_t)t * B_DIM + b) * 64 + i0 + rr] = acc * acc * sg;
        }
    }
}

extern "C" void kernel_launch(void* const* d_in, const int* in_sizes, int n_in,
                              void* d_out, int out_size, void* d_ws, size_t ws_size,
                              hipStream_t stream) {
    const float* x  = (const float*)d_in[0];
    const float* S0 = (const float*)d_in[1];
    const float* Wk = (const float*)d_in[2];
    const float* Wv = (const float*)d_in[3];
    const float* Wq = (const float*)d_in[4];
    const float* uk = (const float*)d_in[5];
    const float* uv = (const float*)d_in[6];

    float* out   = (float*)d_out;                              // [T,B,n]
    float* S_all = out + (size_t)T_DIM * B_DIM * N_DIM;        // [T+1,B,n,n]

    float* ws    = (float*)d_ws;
    float* scale = ws;                                   // 2 floats (pad 64)
    float* kvq   = ws + 64;                              // 16384*192
    unsigned short* BPh = (unsigned short*)(kvq + (size_t)16384 * 192);  // 192*1024
    unsigned short* BPl = BPh + (size_t)192 * D_DIM;
    float* S_init = (float*)(BPl + (size_t)192 * D_DIM); // 16*8*64*64 floats
    float* G      = S_init + (size_t)NCHUNK * 32768;     // 2*64*64 floats

    gram_kernel<<<128, 256, 0, stream>>>(Wk, Wv, G);
    power_kernel<<<2, 64, 0, stream>>>(G, uk, uv, scale);
    build_wt_kernel<<<96, 256, 0, stream>>>(Wk, Wv, Wq, scale, BPh, BPl);
    proj_mfma_kernel<<<T_DIM * B_DIM / PBM, 256, 0, stream>>>(x, BPh, BPl, kvq);
    carry_init_kernel<<<(NCHUNK - 1) * 32, 256, 0, stream>>>(kvq, S_init);
    scan_kernel<<<NCHUNK * B_DIM * 4, 256, 0, stream>>>(kvq, S_init, S0, out, S_all);
}

// Round 13
// 118.459 us; speedup vs baseline: 13.5030x; 1.0141x over previous
//
#include <hip/hip_runtime.h>
#include <math.h>

#define T_DIM 2048
#define B_DIM 8
#define D_DIM 1024
#define N_DIM 64
#define NCHUNK 16
#define CHUNK_LEN 128              // T_DIM / NCHUNK
#define DECAY 0.9f
#define EPS 1e-8f
#define RADIUS 0.5f

typedef __attribute__((ext_vector_type(8))) short short8;   // bf16x8 MFMA frag
typedef __attribute__((ext_vector_type(4))) float f32x4;

static __device__ __forceinline__ unsigned short f2bf(float f) {
    unsigned u = __float_as_uint(f);
    u += 0x7FFFu + ((u >> 16) & 1u);          // RNE
    return (unsigned short)(u >> 16);
}
static __device__ __forceinline__ float bf2f(unsigned short h) {
    return __uint_as_float(((unsigned)h) << 16);
}

// counted barrier: flush LDS writes, sync waves, do NOT drain vmcnt (T4)
static __device__ __forceinline__ void bar_lgkm() {
    asm volatile("s_waitcnt lgkmcnt(0)" ::: "memory");
    __builtin_amdgcn_s_barrier();
    asm volatile("" ::: "memory");
}

// ---------------- Gram matrix: G[mat] = W W^T (64x64), 128 blocks ----------------
__global__ __launch_bounds__(256)
void gram_kernel(const float* __restrict__ Wk, const float* __restrict__ Wv,
                 float* __restrict__ G) {
    int mat = blockIdx.x >> 6;
    int i   = blockIdx.x & 63;
    const float* W = mat ? Wv : Wk;
    __shared__ float wsr[D_DIM];
    __shared__ float part[4][64];
    int tid = threadIdx.x;
    *(float4*)&wsr[tid * 4] = *(const float4*)(W + (size_t)i * D_DIM + tid * 4);
    __syncthreads();
    int j = tid & 63, p = tid >> 6;
    const float* wj = W + (size_t)j * D_DIM + p * 256;
    const float* wp = wsr + p * 256;
    float acc = 0.f;
    #pragma unroll 16
    for (int k = 0; k < 256; k += 4) {
        float4 a = *(const float4*)(wj + k);
        float4 b = *(const float4*)(wp + k);
        acc += a.x * b.x + a.y * b.y + a.z * b.z + a.w * b.w;
    }
    part[p][j] = acc;
    __syncthreads();
    if (tid < 64)
        G[((size_t)mat * 64 + i) * 64 + tid] =
            part[0][tid] + part[1][tid] + part[2][tid] + part[3][tid];
}

// ---------------- power iteration in G-space (exact algebra incl. eps) ----------------
__global__ __launch_bounds__(64)
void power_kernel(const float* __restrict__ G, const float* __restrict__ uk,
                  const float* __restrict__ uv, float* __restrict__ scale_out) {
    __shared__ float Gs[64][65];
    __shared__ float us[64];
    int mat = blockIdx.x;
    int i = threadIdx.x;
    #pragma unroll 8
    for (int r = 0; r < 64; ++r)
        Gs[r][i] = G[((size_t)mat * 64 + r) * 64 + i];
    us[i] = (mat ? uv : uk)[i];
    __syncthreads();
    float sigma = 0.f;
    for (int it = 0; it < 3; ++it) {
        float t = 0.f;
        #pragma unroll
        for (int jj = 0; jj < 64; ++jj)
            t += Gs[i][jj] * us[jj];
        float nv2 = us[i] * t;
        #pragma unroll
        for (int o = 32; o > 0; o >>= 1) nv2 += __shfl_xor(nv2, o, 64);
        float nv = sqrtf(fmaxf(nv2, 0.f));
        float ur = t / (nv + EPS);
        float nu2 = ur * ur;
        #pragma unroll
        for (int o = 32; o > 0; o >>= 1) nu2 += __shfl_xor(nu2, o, 64);
        float nu = sqrtf(nu2);
        if (it == 2) sigma = nu2 / (nu + EPS);
        __syncthreads();
        us[i] = ur / (nu + EPS);
        __syncthreads();
    }
    if (i == 0) scale_out[mat] = RADIUS / (sigma + EPS);
}

// ------- build bf16 hi/lo pack, PACK-LINEAR (coalesced writes) -------
__global__ __launch_bounds__(256)
void build_wt_kernel(const float* __restrict__ Wk, const float* __restrict__ Wv,
                     const float* __restrict__ Wq, const float* __restrict__ scale,
                     unsigned short* __restrict__ BPh, unsigned short* __restrict__ BPl) {
    int bid = blockIdx.x;          // 96 blocks
    int g   = bid >> 3;            // 0..11
    int sub = bid & 7;
    int m   = sub * 256 + threadIdx.x;   // chunk id 0..2047
    int gm  = g >> 2;              // matrix: 0=k,1=v,2=q
    const float* W = (gm == 0) ? Wk : (gm == 1) ? Wv : Wq;
    float sc = (gm == 0) ? scale[0] : (gm == 1) ? scale[1] : 1.0f;
    int s   = m >> 7;
    int kk  = (m >> 6) & 1;
    int flh = (m >> 4) & 3;
    int fl  = m & 15;
    int row = (g & 3) * 16 + fl;
    int k0  = s * 64 + kk * 32 + flh * 8;
    const float* src = W + (size_t)row * D_DIM + k0;
    float4 a = *(const float4*)src;
    float4 b = *(const float4*)(src + 4);
    float v[8] = {a.x, a.y, a.z, a.w, b.x, b.y, b.z, b.w};
    short8 hv, lv;
    #pragma unroll
    for (int e = 0; e < 8; ++e) {
        float val = v[e] * sc;
        unsigned short hh = f2bf(val);
        hv[e] = (short)hh;
        lv[e] = (short)f2bf(val - bf2f(hh));
    }
    size_t o = (size_t)g * 16384 + (size_t)m * 8;
    *(short8*)(BPh + o) = hv;
    *(short8*)(BPl + o) = lv;
}

// ------------- projections: x single bf16, W hi/lo. x-prefetch issued LAST -------------
// (vmcnt retires in issue order: a prefetch issued BEFORE the B loads gets
//  force-drained at the first MFMA wait. Issue it after all B loads instead.)
#define PBM 32
#define KSTAGE 128
__global__ __launch_bounds__(256)
void proj_mfma_kernel(const float* __restrict__ x,
                      const unsigned short* __restrict__ BPh,
                      const unsigned short* __restrict__ BPl,
                      float* __restrict__ kvq) {
    __shared__ __align__(16) unsigned short ldsA[2][PBM * KSTAGE];  // 16 KB
    int tid = threadIdx.x;
    int lane = tid & 63;
    int wv = tid >> 6;                 // 0..3 -> cols [wv*48, +48)
    int fl15 = lane & 15;
    int flh = lane >> 4;               // 0..3
    int rowBase = blockIdx.x * PBM;

    int r_st = tid >> 3;
    int sub  = tid & 7;
    const float* xrow = x + (size_t)(rowBase + r_st) * D_DIM + sub * 8;
    int wb0 = r_st * 256 + ((sub * 16) ^ ((r_st & 7) << 4));
    int wb1 = wb0 + 128;

    const unsigned short* bbh = BPh + (size_t)(wv * 3) * 16384 + lane * 8;
    const unsigned short* bbl = BPl + (size_t)(wv * 3) * 16384 + lane * 8;

    f32x4 acc[2][3];
    #pragma unroll
    for (int mt = 0; mt < 2; ++mt)
        #pragma unroll
        for (int nt = 0; nt < 3; ++nt) acc[mt][nt] = (f32x4)(0.f);

    // prologue: stage 0 -> buf0 (single bf16 plane); stage 1 -> regs p*
    {
        float4 c0 = *(const float4*)(xrow);
        float4 c1 = *(const float4*)(xrow + 4);
        float4 c2 = *(const float4*)(xrow + 64);
        float4 c3 = *(const float4*)(xrow + 68);
        float v0[8] = {c0.x, c0.y, c0.z, c0.w, c1.x, c1.y, c1.z, c1.w};
        float v1[8] = {c2.x, c2.y, c2.z, c2.w, c3.x, c3.y, c3.z, c3.w};
        short8 h0, h1;
        #pragma unroll
        for (int e = 0; e < 8; ++e) {
            h0[e] = (short)f2bf(v0[e]);
            h1[e] = (short)f2bf(v1[e]);
        }
        char* pH = (char*)&ldsA[0][0];
        *(short8*)(pH + wb0) = h0;
        *(short8*)(pH + wb1) = h1;
    }
    float4 p0 = *(const float4*)(xrow + KSTAGE);
    float4 p1 = *(const float4*)(xrow + KSTAGE + 4);
    float4 p2 = *(const float4*)(xrow + KSTAGE + 64);
    float4 p3 = *(const float4*)(xrow + KSTAGE + 68);
    bar_lgkm();

    #pragma unroll 1
    for (int qt = 0; qt < 8; ++qt) {
        int buf = qt & 1;
        const char* pH = (const char*)&ldsA[buf][0];
        #pragma unroll
        for (int s = 0; s < 2; ++s) {
            int sg = qt * 2 + s;
            short8 bh[2][3], bl[2][3];
            #pragma unroll
            for (int nt = 0; nt < 3; ++nt)
                #pragma unroll
                for (int kk = 0; kk < 2; ++kk) {
                    size_t off = (size_t)nt * 16384 + sg * 1024 + kk * 512;
                    bh[kk][nt] = *(const short8*)(bbh + off);
                    bl[kk][nt] = *(const short8*)(bbl + off);
                }
            #pragma unroll
            for (int kk = 0; kk < 2; ++kk) {
                short8 ah[2];
                #pragma unroll
                for (int mt = 0; mt < 2; ++mt) {
                    int row = mt * 16 + fl15;
                    int off = row * 256 + s * 128 +
                              ((kk * 64 + flh * 16) ^ ((row & 7) << 4));
                    ah[mt] = *(const short8*)(pH + off);
                }
                #pragma unroll
                for (int mt = 0; mt < 2; ++mt)
                    #pragma unroll
                    for (int nt = 0; nt < 3; ++nt) {
                        acc[mt][nt] = __builtin_amdgcn_mfma_f32_16x16x32_bf16(
                            ah[mt], bh[kk][nt], acc[mt][nt], 0, 0, 0);
                        acc[mt][nt] = __builtin_amdgcn_mfma_f32_16x16x32_bf16(
                            ah[mt], bl[kk][nt], acc[mt][nt], 0, 0, 0);
                    }
            }
        }
        // ---- x prefetch for stage qt+2, issued AFTER all B loads of this iter ----
        float4 q0, q1, q2, q3;
        if (qt < 6) {
            const float* nx = xrow + (qt + 2) * KSTAGE;
            q0 = *(const float4*)(nx);
            q1 = *(const float4*)(nx + 4);
            q2 = *(const float4*)(nx + 64);
            q3 = *(const float4*)(nx + 68);
        }
        // write stage qt+1 (regs p*, long since complete) into the other buffer
        if (qt < 7) {
            float v0[8] = {p0.x, p0.y, p0.z, p0.w, p1.x, p1.y, p1.z, p1.w};
            float v1[8] = {p2.x, p2.y, p2.z, p2.w, p3.x, p3.y, p3.z, p3.w};
            short8 h0, h1;
            #pragma unroll
            for (int e = 0; e < 8; ++e) {
                h0[e] = (short)f2bf(v0[e]);
                h1[e] = (short)f2bf(v1[e]);
            }
            char* qH = (char*)&ldsA[buf ^ 1][0];
            *(short8*)(qH + wb0) = h0;
            *(short8*)(qH + wb1) = h1;
        }
        bar_lgkm();
        p0 = q0; p1 = q1; p2 = q2; p3 = q3;
    }

    // epilogue: C/D layout col=lane&15, row=(lane>>4)*4+reg  [m89]
    #pragma unroll
    for (int mt = 0; mt < 2; ++mt)
        #pragma unroll
        for (int nt = 0; nt < 3; ++nt) {
            int col = wv * 48 + nt * 16 + fl15;
            #pragma unroll
            for (int r = 0; r < 4; ++r) {
                int row = rowBase + mt * 16 + flh * 4 + r;
                kvq[(size_t)row * 192 + col] = acc[mt][nt][r];
            }
        }
}

// ------------- carry init: S_init[c] = scan of full previous chunk -------------
__global__ __launch_bounds__(256)
void carry_init_kernel(const float* __restrict__ kvq,
                       float* __restrict__ S_init) {
    int blk = blockIdx.x;          // 0..479
    int c   = (blk >> 5) + 1;      // 1..15
    int rem = blk & 31;
    int b   = rem >> 2;
    int iq  = rem & 3;
    int i   = iq * 16 + (threadIdx.x >> 4);
    int j4  = (threadIdx.x & 15) * 4;
    int tp  = (c - 1) * CHUNK_LEN;
    float4 s4 = {0.f, 0.f, 0.f, 0.f};
    #pragma unroll 4
    for (int u = 0; u < CHUNK_LEN; ++u) {
        const float* base = kvq + (size_t)((tp + u) * B_DIM + b) * 192;
        float v = base[64 + i];
        float4 k4 = *(const float4*)(base + j4);
        s4.x = __builtin_fmaf(DECAY, s4.x, v * k4.x);
        s4.y = __builtin_fmaf(DECAY, s4.y, v * k4.y);
        s4.z = __builtin_fmaf(DECAY, s4.z, v * k4.z);
        s4.w = __builtin_fmaf(DECAY, s4.w, v * k4.w);
    }
    *(float4*)&S_init[(((size_t)c * B_DIM + b) * 64 + i) * 64 + j4] = s4;
}

// ------------- scan: lane = (r,jq) holds S[i0+r][4jq..+3]; dwordx4 NT stores -------------
#define SC_TILE 8
__global__ __launch_bounds__(256)
void scan_kernel(const float* __restrict__ kvq,
                 const float* __restrict__ S_init,
                 const float* __restrict__ S0,
                 float* __restrict__ out,      // [T,B,n]
                 float* __restrict__ S_all) {  // [T+1,B,n,n]
    __shared__ __align__(16) float P[4][SC_TILE][4][20];
    int widL = threadIdx.x >> 6;
    int lane = threadIdx.x & 63;
    int r  = lane >> 4;          // row within wave's 4
    int jq = lane & 15;          // col quad
    int blk = blockIdx.x;
    int c  = blk >> 5;           // 0..15
    int b  = (blk >> 2) & 7;
    int ig = blk & 3;
    int i0 = ig * 16 + widL * 4;
    int i  = i0 + r;

    int pp   = lane >> 1;
    int ur   = pp >> 2;
    int rr   = pp & 3;
    int half = lane & 1;

    if (c == 0) {
        f32x4 s0v = *(const f32x4*)&S0[((size_t)b * 64 + i) * 64 + jq * 4];
        *(f32x4*)&S_all[(size_t)b * 4096 + (size_t)i * 64 + jq * 4] = s0v;
    }

    f32x4 s = (f32x4)(0.f);
    if (c > 0)
        s = *(const f32x4*)&S_init[(((size_t)c * B_DIM + b) * 64 + i) * 64 + jq * 4];

    int t0 = c * CHUNK_LEN;
    for (int tb = 0; tb < CHUNK_LEN; tb += SC_TILE) {
        #pragma unroll
        for (int u = 0; u < SC_TILE; ++u) {
            int t = t0 + tb + u;
            const float* base = kvq + (size_t)(t * B_DIM + b) * 192;
            f32x4 k4 = *(const f32x4*)(base + jq * 4);
            f32x4 q4 = *(const f32x4*)(base + 128 + jq * 4);
            float v  = base[64 + i];
            s.x = __builtin_fmaf(DECAY, s.x, v * k4.x);
            s.y = __builtin_fmaf(DECAY, s.y, v * k4.y);
            s.z = __builtin_fmaf(DECAY, s.z, v * k4.z);
            s.w = __builtin_fmaf(DECAY, s.w, v * k4.w);
            __builtin_nontemporal_store(
                s, (f32x4*)&S_all[((size_t)(t + 1) * B_DIM + b) * 4096 +
                                  (size_t)i * 64 + jq * 4]);
            P[widL][u][r][jq] = s.x * q4.x + s.y * q4.y + s.z * q4.z + s.w * q4.w;
        }
        const float* pr = &P[widL][ur][rr][half * 8];
        f32x4 a0 = *(const f32x4*)pr;
        f32x4 a1 = *(const f32x4*)(pr + 4);
        float acc = (a0.x + a0.y) + (a0.z + a0.w) + (a1.x + a1.y) + (a1.z + a1.w);
        acc += __shfl_xor(acc, 1, 64);
        if (half == 0) {
            int t = t0 + tb + ur;
            float sg = 1.0f / (1.0f + __expf(-acc));
            out[((size_t)t * B_DIM + b) * 64 + i0 + rr] = acc * acc * sg;
        }
    }
}

extern "C" void kernel_launch(void* const* d_in, const int* in_sizes, int n_in,
                              void* d_out, int out_size, void* d_ws, size_t ws_size,
                              hipStream_t stream) {
    const float* x  = (const float*)d_in[0];
    const float* S0 = (const float*)d_in[1];
    const float* Wk = (const float*)d_in[2];
    const float* Wv = (const float*)d_in[3];
    const float* Wq = (const float*)d_in[4];
    const float* uk = (const float*)d_in[5];
    const float* uv = (const float*)d_in[6];

    float* out   = (float*)d_out;                              // [T,B,n]
    float* S_all = out + (size_t)T_DIM * B_DIM * N_DIM;        // [T+1,B,n,n]

    float* ws    = (float*)d_ws;
    float* scale = ws;                                   // 2 floats (pad 64)
    float* kvq   = ws + 64;                              // 16384*192
    unsigned short* BPh = (unsigned short*)(kvq + (size_t)16384 * 192);  // 192*1024
    unsigned short* BPl = BPh + (size_t)192 * D_DIM;
    float* S_init = (float*)(BPl + (size_t)192 * D_DIM); // 16*8*64*64 floats
    float* G      = S_init + (size_t)NCHUNK * 32768;     // 2*64*64 floats

    gram_kernel<<<128, 256, 0, stream>>>(Wk, Wv, G);
    power_kernel<<<2, 64, 0, stream>>>(G, uk, uv, scale);
    build_wt_kernel<<<96, 256, 0, stream>>>(Wk, Wv, Wq, scale, BPh, BPl);
    proj_mfma_kernel<<<T_DIM * B_DIM / PBM, 256, 0, stream>>>(x, BPh, BPl, kvq);
    carry_init_kernel<<<(NCHUNK - 1) * 32, 256, 0, stream>>>(kvq, S_init);
    scan_kernel<<<NCHUNK * B_DIM * 4, 256, 0, stream>>>(kvq, S_init, S0, out, S_all);
}